// Round 5
// baseline (59.257 us; speedup 1.0000x reference)
//
#include <hip/hip_runtime.h>
#include <math.h>

// LayerStatistics: out = (x copy [N floats], stats[5] = mean, sqmean, var(ddof=1), min, max)
// x: (32,64,128,128) fp32, N = 33554432.
// Two-dispatch structure (single-kernel atomic rendezvous measured 2-3x slower
// on gfx950: same-address device-scope RMWs serialize at the fabric coherence
// point, and plain-store partials would be stale across non-coherent XCD L2s).
// Pass1: fused copy + partial reduce, 8 independent loads in flight per thread.
// Pass2: one wave (64 threads), pure shuffle reduce — minimal dispatch cost.

constexpr int BLOCK = 256;
constexpr int GRID  = 2048;   // 256 CU * 8 blocks/CU = 32 waves/CU

typedef float v4f __attribute__((ext_vector_type(4)));

__global__ __launch_bounds__(BLOCK) void stats_pass1(const v4f* __restrict__ in,
                                                     v4f* __restrict__ out,
                                                     float4* __restrict__ partials,
                                                     int n4) {
    const int tid    = blockIdx.x * blockDim.x + threadIdx.x;
    const int stride = gridDim.x * blockDim.x;

    float s  = 0.0f;
    float ss = 0.0f;
    float mn =  INFINITY;
    float mx = -INFINITY;

    if ((n4 & (8 * stride - 1)) == 0) {
        // fast path: 8 independent 16B loads in flight, then 8 stores
        for (int i = tid; i < n4; i += 8 * stride) {
            v4f v[8];
            #pragma unroll
            for (int k = 0; k < 8; ++k) v[k] = in[i + k * stride];
            #pragma unroll
            for (int k = 0; k < 8; ++k) out[i + k * stride] = v[k];
            #pragma unroll
            for (int k = 0; k < 8; ++k) {
                float a0 = v[k][0], a1 = v[k][1], a2 = v[k][2], a3 = v[k][3];
                s  += (a0 + a1) + (a2 + a3);
                ss += (a0 * a0 + a1 * a1) + (a2 * a2 + a3 * a3);
                mn = fminf(mn, fminf(fminf(a0, a1), fminf(a2, a3)));
                mx = fmaxf(mx, fmaxf(fmaxf(a0, a1), fmaxf(a2, a3)));
            }
        }
    } else {
        for (int i = tid; i < n4; i += stride) {
            v4f v = in[i];
            out[i] = v;
            #pragma unroll
            for (int e = 0; e < 4; ++e) {
                float a = v[e];
                s  += a;
                ss += a * a;
                mn = fminf(mn, a);
                mx = fmaxf(mx, a);
            }
        }
    }

    // wave (64-lane) reduce
    #pragma unroll
    for (int off = 32; off > 0; off >>= 1) {
        s  += __shfl_down(s,  off, 64);
        ss += __shfl_down(ss, off, 64);
        mn = fminf(mn, __shfl_down(mn, off, 64));
        mx = fmaxf(mx, __shfl_down(mx, off, 64));
    }

    __shared__ float4 red[BLOCK / 64];
    const int lane = threadIdx.x & 63;
    const int wave = threadIdx.x >> 6;
    if (lane == 0) red[wave] = make_float4(s, ss, mn, mx);
    __syncthreads();

    if (threadIdx.x == 0) {
        float4 a = red[0];
        #pragma unroll
        for (int w = 1; w < BLOCK / 64; ++w) {
            float4 b = red[w];
            a.x += b.x;
            a.y += b.y;
            a.z = fminf(a.z, b.z);
            a.w = fmaxf(a.w, b.w);
        }
        partials[blockIdx.x] = a;
    }
}

// Pass 2: ONE wave reduces GRID partials; double accumulation for sum/sumsq.
__global__ __launch_bounds__(64) void stats_pass2(const float4* __restrict__ partials,
                                                  float* __restrict__ stats_out,
                                                  int nparts, double n_total) {
    double s  = 0.0;
    double ss = 0.0;
    float  mn =  INFINITY;
    float  mx = -INFINITY;

    for (int i = threadIdx.x; i < nparts; i += 64) {
        float4 p = partials[i];
        s  += (double)p.x;
        ss += (double)p.y;
        mn = fminf(mn, p.z);
        mx = fmaxf(mx, p.w);
    }

    #pragma unroll
    for (int off = 32; off > 0; off >>= 1) {
        s  += __shfl_down(s,  off, 64);
        ss += __shfl_down(ss, off, 64);
        mn = fminf(mn, __shfl_down(mn, off, 64));
        mx = fmaxf(mx, __shfl_down(mx, off, 64));
    }

    if (threadIdx.x == 0) {
        double mean   = s / n_total;
        double sqmean = ss / n_total;
        double var    = (ss - s * s / n_total) / (n_total - 1.0);
        stats_out[0] = (float)mean;
        stats_out[1] = (float)sqmean;
        stats_out[2] = (float)var;
        stats_out[3] = mn;
        stats_out[4] = mx;
    }
}

extern "C" void kernel_launch(void* const* d_in, const int* in_sizes, int n_in,
                              void* d_out, int out_size, void* d_ws, size_t ws_size,
                              hipStream_t stream) {
    const float* x  = (const float*)d_in[0];
    float* out      = (float*)d_out;
    int n  = in_sizes[0];          // 33554432
    int n4 = n / 4;                // 8388608

    float4* partials = (float4*)d_ws;   // GRID * 16 B = 32 KiB

    stats_pass1<<<GRID, BLOCK, 0, stream>>>((const v4f*)x, (v4f*)out, partials, n4);
    stats_pass2<<<1, 64, 0, stream>>>(partials, out + n, GRID, (double)n);
}

// Round 7
// 51.947 us; speedup vs baseline: 1.1407x; 1.1407x over previous
//
#include <hip/hip_runtime.h>
#include <math.h>

// LayerStatistics: out = (x copy [N floats], stats[5] = mean, sqmean, var(ddof=1), min, max)
// x: (32,64,128,128) fp32, N = 33554432.
// PROVEN BEST (50.78 us timed): two-dispatch structure.
//  - Single-kernel fusion is dead on gfx950: agent-scope fence = L2 writeback
//    per block (200 us); same-address device atomics serialize at the fabric
//    (170 us). Thin 1-wave pass2 costs +8 us (serial cross-XCD loads).
//  - sc1/nt write-around stores are INCORRECT: they race dirty L2 lines left
//    by the harness's cached memset (round-6 failure). __builtin_nontemporal_store
//    (through-L2 nt hint) is safe and neutral.
// Pass1: fused copy + partial reduce, 4 independent loads in flight.
// Pass2: one 256-thread block, grid-stride over 2048 partials, double accum.

constexpr int BLOCK = 256;
constexpr int GRID  = 2048;   // 256 CU * 8 blocks/CU = 32 waves/CU

typedef float v4f __attribute__((ext_vector_type(4)));

__global__ __launch_bounds__(BLOCK) void stats_pass1(const v4f* __restrict__ in,
                                                     v4f* __restrict__ out,
                                                     float4* __restrict__ partials,
                                                     int n4) {
    const int tid    = blockIdx.x * blockDim.x + threadIdx.x;
    const int stride = gridDim.x * blockDim.x;

    float s  = 0.0f;
    float ss = 0.0f;
    float mn =  INFINITY;
    float mx = -INFINITY;

    if ((n4 & (4 * stride - 1)) == 0) {
        // fast path: 4 independent loads in flight per iteration
        for (int i = tid; i < n4; i += 4 * stride) {
            v4f v0 = in[i];
            v4f v1 = in[i + stride];
            v4f v2 = in[i + 2 * stride];
            v4f v3 = in[i + 3 * stride];
            __builtin_nontemporal_store(v0, &out[i]);
            __builtin_nontemporal_store(v1, &out[i + stride]);
            __builtin_nontemporal_store(v2, &out[i + 2 * stride]);
            __builtin_nontemporal_store(v3, &out[i + 3 * stride]);
            #pragma unroll
            for (int e = 0; e < 4; ++e) {
                float a0 = v0[e], a1 = v1[e], a2 = v2[e], a3 = v3[e];
                s  += (a0 + a1) + (a2 + a3);
                ss += (a0 * a0 + a1 * a1) + (a2 * a2 + a3 * a3);
                mn = fminf(mn, fminf(fminf(a0, a1), fminf(a2, a3)));
                mx = fmaxf(mx, fmaxf(fmaxf(a0, a1), fmaxf(a2, a3)));
            }
        }
    } else {
        for (int i = tid; i < n4; i += stride) {
            v4f v = in[i];
            __builtin_nontemporal_store(v, &out[i]);
            #pragma unroll
            for (int e = 0; e < 4; ++e) {
                float a = v[e];
                s  += a;
                ss += a * a;
                mn = fminf(mn, a);
                mx = fmaxf(mx, a);
            }
        }
    }

    // wave (64-lane) reduce
    #pragma unroll
    for (int off = 32; off > 0; off >>= 1) {
        s  += __shfl_down(s,  off, 64);
        ss += __shfl_down(ss, off, 64);
        mn = fminf(mn, __shfl_down(mn, off, 64));
        mx = fmaxf(mx, __shfl_down(mx, off, 64));
    }

    __shared__ float4 red[BLOCK / 64];
    const int lane = threadIdx.x & 63;
    const int wave = threadIdx.x >> 6;
    if (lane == 0) red[wave] = make_float4(s, ss, mn, mx);
    __syncthreads();

    if (threadIdx.x == 0) {
        float4 a = red[0];
        #pragma unroll
        for (int w = 1; w < BLOCK / 64; ++w) {
            float4 b = red[w];
            a.x += b.x;
            a.y += b.y;
            a.z = fminf(a.z, b.z);
            a.w = fmaxf(a.w, b.w);
        }
        partials[blockIdx.x] = a;
    }
}

// Pass 2: single block reduces GRID partials; double accumulation for sum/sumsq.
__global__ __launch_bounds__(BLOCK) void stats_pass2(const float4* __restrict__ partials,
                                                     float* __restrict__ stats_out,
                                                     int nparts, double n_total) {
    double s  = 0.0;
    double ss = 0.0;
    float  mn =  INFINITY;
    float  mx = -INFINITY;

    for (int i = threadIdx.x; i < nparts; i += blockDim.x) {
        float4 p = partials[i];
        s  += (double)p.x;
        ss += (double)p.y;
        mn = fminf(mn, p.z);
        mx = fmaxf(mx, p.w);
    }

    #pragma unroll
    for (int off = 32; off > 0; off >>= 1) {
        s  += __shfl_down(s,  off, 64);
        ss += __shfl_down(ss, off, 64);
        mn = fminf(mn, __shfl_down(mn, off, 64));
        mx = fmaxf(mx, __shfl_down(mx, off, 64));
    }

    __shared__ double sred[BLOCK / 64];
    __shared__ double ssred[BLOCK / 64];
    __shared__ float  mnred[BLOCK / 64];
    __shared__ float  mxred[BLOCK / 64];
    int lane = threadIdx.x & 63;
    int wave = threadIdx.x >> 6;
    if (lane == 0) { sred[wave] = s; ssred[wave] = ss; mnred[wave] = mn; mxred[wave] = mx; }
    __syncthreads();

    if (threadIdx.x == 0) {
        #pragma unroll
        for (int w = 1; w < BLOCK / 64; ++w) {
            s  += sred[w];
            ss += ssred[w];
            mn = fminf(mn, mnred[w]);
            mx = fmaxf(mx, mxred[w]);
        }
        double mean   = s / n_total;
        double sqmean = ss / n_total;
        double var    = (ss - s * s / n_total) / (n_total - 1.0);
        stats_out[0] = (float)mean;
        stats_out[1] = (float)sqmean;
        stats_out[2] = (float)var;
        stats_out[3] = mn;
        stats_out[4] = mx;
    }
}

extern "C" void kernel_launch(void* const* d_in, const int* in_sizes, int n_in,
                              void* d_out, int out_size, void* d_ws, size_t ws_size,
                              hipStream_t stream) {
    const float* x  = (const float*)d_in[0];
    float* out      = (float*)d_out;
    int n  = in_sizes[0];          // 33554432
    int n4 = n / 4;                // 8388608

    float4* partials = (float4*)d_ws;   // GRID * 16 B = 32 KiB

    stats_pass1<<<GRID, BLOCK, 0, stream>>>((const v4f*)x, (v4f*)out, partials, n4);
    stats_pass2<<<1, BLOCK, 0, stream>>>(partials, out + n, GRID, (double)n);
}